// Round 3
// baseline (291.479 us; speedup 1.0000x reference)
//
#include <hip/hip_runtime.h>
#include <cstdint>
#include <cstddef>

#define NTOT  22743      // 1083 + 4332 + 17328
#define NPAD  22784      // NTOT rounded up to multiple of 64 (wave-uniform image id)
#define N1    1083
#define N12   5415
#define BATCH 64
#define KCAND 512
#define CAP   4096       // per-(image,class) candidate capacity (~1830 expected)
#define MAXPC 100
#define MAXTOT 100

__device__ __forceinline__ float sigmoidf(float x) { return 1.0f / (1.0f + expf(-x)); }

// ---------------------------------------------------------------- kernel 0
__global__ void zero_counts(uint32_t* counts) { counts[threadIdx.x] = 0u; }

// ---------------------------------------------------------------- kernel 1
// score + filter: append (score_bits, box_idx) to per-(b,c) global lists.
// Wave-aggregated atomics: 1 global atomicAdd per wave per class.
__global__ __launch_bounds__(256) void score_filter_kernel(
    const float* __restrict__ p1, const float* __restrict__ p2,
    const float* __restrict__ p3, uint2* __restrict__ cand,
    uint32_t* __restrict__ counts)
{
  const int u   = blockIdx.x * 256 + threadIdx.x;
  const int b   = u / NPAD;                  // wave-uniform (NPAD % 64 == 0)
  const int i   = u - b * NPAD;
  const int lane = threadIdx.x & 63;
  const bool active = (i < NTOT);

  float s0 = 0.f, s1 = 0.f;
  if (active) {
    const float* p; int local, per;
    if (i < N1)       { p = p1; local = i;        per = 1083; }
    else if (i < N12) { p = p2; local = i - N1;   per = 4332; }
    else              { p = p3; local = i - N12;  per = 17328; }
    const float* q = p + ((size_t)b * per + local) * 7;
    float q4 = q[4];
    if (q4 > 0.f) {              // else sig(q4)<=0.5 -> product < 0.5 strictly
      float obj = sigmoidf(q4);
      s0 = obj * sigmoidf(q[5]);
      s1 = obj * sigmoidf(q[6]);
    }
  }

  #pragma unroll
  for (int c = 0; c < 2; c++) {
    float s = (c == 0) ? s0 : s1;
    bool pred = s > 0.5f;
    unsigned long long m = __ballot(pred ? 1 : 0);
    if (m != 0ull) {
      int leader = (int)__ffsll((unsigned long long)m) - 1;
      uint32_t base = 0u;
      if (lane == leader) base = atomicAdd(&counts[b * 2 + c], (uint32_t)__popcll(m));
      base = (uint32_t)__shfl((int)base, leader);
      if (pred) {
        uint32_t off = base + (uint32_t)__popcll(m & ((1ull << lane) - 1ull));
        if (off < CAP)
          cand[(size_t)(b * 2 + c) * CAP + off] = make_uint2(__float_as_uint(s), (uint32_t)i);
      }
    }
  }
}

// box decode for global candidate index i of image b
__device__ void decode_box(const float* __restrict__ p1, const float* __restrict__ p2,
                           const float* __restrict__ p3, const float* __restrict__ anch,
                           int b, int i, float bb[4])
{
  const float* p; int local, g, abase, per;
  if (i < N1)       { p = p1; local = i;       g = 19; abase = 6; per = 1083; }
  else if (i < N12) { p = p2; local = i - N1;  g = 38; abase = 3; per = 4332; }
  else              { p = p3; local = i - N12; g = 76; abase = 0; per = 17328; }
  const float* q = p + ((size_t)b * per + local) * 7;
  int a    = local % 3;
  int cell = local / 3;
  int col  = cell % g;
  int row  = cell / g;
  float aw = anch[(abase + a) * 2 + 0];
  float ah = anch[(abase + a) * 2 + 1];
  float x = (sigmoidf(q[0]) + (float)col) / (float)g;
  float y = (sigmoidf(q[1]) + (float)row) / (float)g;
  float w = expf(q[2]) * aw;
  float h = expf(q[3]) * ah;
  float x1 = x - w * 0.5f;
  float y1 = y - h * 0.5f;
  bb[0] = x1; bb[1] = y1; bb[2] = x1 + w; bb[3] = y1 + h;
}

// ---------------------------------------------------------------- kernel 2
// one block (512 thr) per (image, class): load candidate list, radix-select
// 512th key, collect >= K (ballot-aggregated), rank-by-count sort (1 barrier),
// decode boxes, register-kept-list NMS on wave 0, ballot compaction.
__global__ __launch_bounds__(512) void nms_kernel(
    const uint2* __restrict__ cand, const uint32_t* __restrict__ counts,
    const float* __restrict__ p1, const float* __restrict__ p2,
    const float* __restrict__ p3, const float* __restrict__ anch,
    float* __restrict__ selScore, float* __restrict__ selBox,
    int* __restrict__ selRank, int* __restrict__ selCount)
{
  const int bc   = blockIdx.x;   // b*2 + c
  const int b    = bc >> 1;
  const int tid  = threadIdx.x;
  const int lane = tid & 63;

  __shared__ uint2    kv[CAP];          // 32 KB candidate list
  __shared__ uint2    ukv[1024];        //  8 KB collected (unsorted)
  __shared__ uint32_t skey[512];        //  sorted keys
  __shared__ uint32_t sidx[512];        //  sorted indices
  __shared__ float    bxs[512][4];
  __shared__ float    sarea[512];
  __shared__ uint32_t pos[512];
  __shared__ uint32_t hist[256];
  __shared__ uint32_t svar[8];

  int n = (int)counts[bc]; if (n > CAP) n = CAP;

  for (int i = tid; i < n; i += 512) kv[i] = cand[(size_t)bc * CAP + i];
  if (tid == 0) { svar[0] = 0x3F000000u; svar[2] = KCAND; svar[4] = 0u; }
  if (tid < 512) { skey[tid] = 0u; sidx[tid] = 0xFFFFFFFFu; }
  __syncthreads();

  // ---- radix select (LDS): exact key of the 512th largest.
  // keys in (0x3F000000, 0x3F800000) -> top byte fixed 0x3F, scan bytes 2,1,0
  uint32_t K = 0u;
  if (n > KCAND) {
    #pragma unroll
    for (int p = 0; p < 3; p++) {
      const int shift = 16 - 8 * p;
      const uint32_t maskB = (p == 0) ? 0xFF000000u : (p == 1) ? 0xFFFF0000u : 0xFFFFFF00u;
      if (tid < 256) hist[tid] = 0u;
      __syncthreads();
      const uint32_t prefix = svar[0];
      for (int i = tid; i < n; i += 512) {
        uint32_t k = kv[i].x;
        if ((k & maskB) == prefix) atomicAdd(&hist[(k >> shift) & 255u], 1u);
      }
      __syncthreads();
      if (tid < 64) {                       // wave-parallel suffix-scan select
        uint32_t h0 = hist[lane * 4 + 0], h1 = hist[lane * 4 + 1];
        uint32_t h2 = hist[lane * 4 + 2], h3 = hist[lane * 4 + 3];
        uint32_t s3 = h3, s2 = h2 + s3, s1 = h1 + s2, s0 = h0 + s1;
        uint32_t acc = s0;
        #pragma unroll
        for (int off = 1; off < 64; off <<= 1) {
          uint32_t v = __shfl_down(acc, (unsigned)off);
          acc += (lane + off < 64) ? v : 0u;
        }
        uint32_t above = acc - s0;          // sum over bins >= (lane+1)*4
        uint32_t S0 = above + s0, S1 = above + s1, S2 = above + s2, S3 = above + s3, S4 = above;
        uint32_t nd = svar[2];
        if (S0 >= nd && S1 < nd) { svar[0] = prefix | ((uint32_t)(lane * 4 + 0) << shift); svar[2] = nd - S1; }
        if (S1 >= nd && S2 < nd) { svar[0] = prefix | ((uint32_t)(lane * 4 + 1) << shift); svar[2] = nd - S2; }
        if (S2 >= nd && S3 < nd) { svar[0] = prefix | ((uint32_t)(lane * 4 + 2) << shift); svar[2] = nd - S3; }
        if (S3 >= nd && S4 < nd) { svar[0] = prefix | ((uint32_t)(lane * 4 + 3) << shift); svar[2] = nd - S4; }
      }
      __syncthreads();
    }
    K = svar[0];
  }

  // ---- collect keys >= K (ballot-aggregated appends; ~513 entries)
  const int nr = (n + 511) & ~511;
  for (int i = tid; i < nr; i += 512) {
    bool pred = (i < n) && (kv[i].x >= K);
    unsigned long long m = __ballot(pred ? 1 : 0);
    if (m != 0ull) {
      int leader = (int)__ffsll((unsigned long long)m) - 1;
      uint32_t base = 0u;
      if (lane == leader) base = atomicAdd(&svar[4], (uint32_t)__popcll(m));
      base = (uint32_t)__shfl((int)base, leader);
      if (pred) {
        uint32_t q = base + (uint32_t)__popcll(m & ((1ull << lane) - 1ull));
        if (q < 1024u) ukv[q] = kv[i];
      }
    }
  }
  __syncthreads();
  int mcnt = (int)svar[4]; if (mcnt > 1024) mcnt = 1024;

  // ---- rank-by-count sort: desc by key, ties asc by index (1 barrier)
  for (int t = tid; t < mcnt; t += 512) {
    uint2 e = ukv[t];
    int rank = 0;
    #pragma unroll 4
    for (int j = 0; j < mcnt; j++) {
      uint2 f = ukv[j];
      rank += (int)((f.x > e.x) || (f.x == e.x && f.y < e.y));
    }
    if (rank < 512) { skey[rank] = e.x; sidx[rank] = e.y; }
  }
  __syncthreads();

  const int limit = (n < KCAND) ? n : KCAND;   // all entries < limit have score > 0.5

  // ---- decode boxes for ranks [0, 512)
  if (tid < 512) {
    float bb[4] = {0.f, 0.f, 0.f, 0.f};
    if (tid < limit) decode_box(p1, p2, p3, anch, b, (int)sidx[tid], bb);
    bxs[tid][0] = bb[0]; bxs[tid][1] = bb[1]; bxs[tid][2] = bb[2]; bxs[tid][3] = bb[3];
    sarea[tid] = fmaxf(bb[2] - bb[0], 0.f) * fmaxf(bb[3] - bb[1], 0.f);
  }
  __syncthreads();

  // ---- greedy NMS on wave 0; kept list lives in registers (2 slots/lane)
  if (tid < 64) {
    float k0x1 = 0.f, k0y1 = 0.f, k0x2 = 0.f, k0y2 = 0.f, k0a = 0.f;
    float k1x1 = 0.f, k1y1 = 0.f, k1x2 = 0.f, k1y2 = 0.f, k1a = 0.f;
    int kept = 0;
    uint32_t keepbits = 0u;
    float c0 = 0.f, c1 = 0.f, c2 = 0.f, c3 = 0.f, ca = 0.f;
    if (limit > 0) {
      float4 cb = *(const float4*)bxs[0];
      c0 = cb.x; c1 = cb.y; c2 = cb.z; c3 = cb.w; ca = sarea[0];
    }
    for (int i = 0; i < limit; i++) {
      int ip = (i + 1 < limit) ? (i + 1) : i;
      float4 nb = *(const float4*)bxs[ip];       // prefetch next (broadcast read)
      float na = sarea[ip];
      bool ov;
      {
        float iw = fmaxf(fminf(c2, k0x2) - fmaxf(c0, k0x1), 0.f);
        float ih = fmaxf(fminf(c3, k0y2) - fmaxf(c1, k0y1), 0.f);
        float inter = iw * ih;
        float uni = fmaxf(ca + k0a - inter, 1e-9f);
        ov = (lane < kept) && (inter / uni > 0.5f);
      }
      {
        float iw = fmaxf(fminf(c2, k1x2) - fmaxf(c0, k1x1), 0.f);
        float ih = fmaxf(fminf(c3, k1y2) - fmaxf(c1, k1y1), 0.f);
        float inter = iw * ih;
        float uni = fmaxf(ca + k1a - inter, 1e-9f);
        ov |= (64 + lane < kept) && (inter / uni > 0.5f);
      }
      if (!__any(ov)) {
        if (lane == (kept & 63)) {
          if (kept < 64) { k0x1 = c0; k0y1 = c1; k0x2 = c2; k0y2 = c3; k0a = ca; }
          else           { k1x1 = c0; k1y1 = c1; k1x2 = c2; k1y2 = c3; k1a = ca; }
        }
        if (lane == (i & 63)) keepbits |= (1u << (i >> 6));
        kept++;
        if (kept >= MAXPC) break;    // cumsum(keep) <= 100 drops anything later
      }
      c0 = nb.x; c1 = nb.y; c2 = nb.z; c3 = nb.w; ca = na;
    }
    // ---- ballot-based compaction positions
    uint32_t total = 0u;
    #pragma unroll
    for (int t = 0; t < 8; t++) {
      unsigned long long m = __ballot((int)((keepbits >> t) & 1u));
      uint32_t pre = total + (uint32_t)__popcll(m & ((1ull << lane) - 1ull));
      pos[t * 64 + lane] = ((keepbits >> t) & 1u) ? pre : 0xFFFFFFFFu;
      total += (uint32_t)__popcll(m);
    }
    if (lane == 0) selCount[bc] = (int)total;   // <= 100 by construction
  }
  __syncthreads();

  // ---- write kept entries (order preserved)
  if (tid < 512) {
    uint32_t p = pos[tid];
    if (p < MAXPC) {
      selScore[bc * MAXPC + p] = __uint_as_float(skey[tid]);
      selRank[bc * MAXPC + p]  = tid;
      float* o = &selBox[(size_t)(bc * MAXPC + p) * 4];
      o[0] = bxs[tid][0]; o[1] = bxs[tid][1]; o[2] = bxs[tid][2]; o[3] = bxs[tid][3];
    }
  }
}

// ---------------------------------------------------------------- kernel 3
// per image: merge the two class lists (<=200), exact top-100 by
// (score desc, flat index asc) via rank-by-count, write outputs.
__global__ __launch_bounds__(256) void merge_kernel(
    const float* __restrict__ selScore, const float* __restrict__ selBox,
    const int* __restrict__ selRank, const int* __restrict__ selCount,
    float* __restrict__ out)
{
  const int b   = blockIdx.x;
  const int tid = threadIdx.x;
  __shared__ float    es[200];
  __shared__ uint32_t ek[200];
  __shared__ float    eb[200][4];
  const int c0  = selCount[b * 2 + 0];
  const int c1  = selCount[b * 2 + 1];
  const int tot = c0 + c1;                      // <= 200

  if (tid < tot) {
    int cls  = (tid < c0) ? 0 : 1;
    int slot = (cls == 0) ? tid : (tid - c0);
    int src  = (b * 2 + cls) * MAXPC + slot;
    es[tid] = selScore[src];
    ek[tid] = (uint32_t)(cls * KCAND + selRank[src]);   // flat index in (2,512)
    eb[tid][0] = selBox[(size_t)src * 4 + 0];
    eb[tid][1] = selBox[(size_t)src * 4 + 1];
    eb[tid][2] = selBox[(size_t)src * 4 + 2];
    eb[tid][3] = selBox[(size_t)src * 4 + 3];
  }
  __syncthreads();

  float* outBoxes  = out;
  float* outScores = out + (size_t)BATCH * MAXTOT * 4;
  float* outCls    = outScores + (size_t)BATCH * MAXTOT;
  float* outCnt    = outCls + (size_t)BATCH * MAXTOT;
  const int filled = (tot < MAXTOT) ? tot : MAXTOT;

  if (tid < tot) {
    float    s  = es[tid];
    uint32_t fk = ek[tid];
    int rank = 0;
    for (int j = 0; j < tot; j++)
      rank += (int)((es[j] > s) || (es[j] == s && ek[j] < fk));
    if (rank < MAXTOT) {                       // kept: s > 0.5 > 0 always
      outScores[b * MAXTOT + rank] = s;
      outCls[b * MAXTOT + rank]    = (float)(fk >> 9);
      float* ob = &outBoxes[(size_t)(b * MAXTOT + rank) * 4];
      ob[0] = fminf(fmaxf(eb[tid][0], 0.f), 1.f);
      ob[1] = fminf(fmaxf(eb[tid][1], 0.f), 1.f);
      ob[2] = fminf(fmaxf(eb[tid][2], 0.f), 1.f);
      ob[3] = fminf(fmaxf(eb[tid][3], 0.f), 1.f);
    }
  }
  if (tid >= filled && tid < MAXTOT) {         // zero-fill unused slots
    outScores[b * MAXTOT + tid] = 0.f;
    outCls[b * MAXTOT + tid]    = 0.f;
    float* ob = &outBoxes[(size_t)(b * MAXTOT + tid) * 4];
    ob[0] = 0.f; ob[1] = 0.f; ob[2] = 0.f; ob[3] = 0.f;
  }
  if (tid == 0) outCnt[b] = (float)filled;
}

// ---------------------------------------------------------------- launch
extern "C" void kernel_launch(void* const* d_in, const int* in_sizes, int n_in,
                              void* d_out, int out_size, void* d_ws, size_t ws_size,
                              hipStream_t stream)
{
  const float* p1   = (const float*)d_in[0];
  const float* p2   = (const float*)d_in[1];
  const float* p3   = (const float*)d_in[2];
  const float* anch = (const float*)d_in[3];

  uint8_t* ws = (uint8_t*)d_ws;
  uint32_t* counts  = (uint32_t*)ws;                               // 128 u32
  uint2*    cand    = (uint2*)(ws + 1024);                         // 128*4096 uint2 = 4 MB
  float*    selScore= (float*)(ws + 1024 + (size_t)128 * CAP * 8); // 128*100 f32
  float*    selBox  = selScore + BATCH * 2 * MAXPC;                // 128*100*4 f32
  int*      selRank = (int*)(selBox + (size_t)BATCH * 2 * MAXPC * 4);
  int*      selCount= selRank + BATCH * 2 * MAXPC;                 // 128 int

  zero_counts<<<1, 128, 0, stream>>>(counts);
  score_filter_kernel<<<(BATCH * NPAD) / 256, 256, 0, stream>>>(p1, p2, p3, cand, counts);
  nms_kernel<<<BATCH * 2, 512, 0, stream>>>(cand, counts, p1, p2, p3, anch,
                                            selScore, selBox, selRank, selCount);
  merge_kernel<<<BATCH, 256, 0, stream>>>(selScore, selBox, selRank, selCount,
                                          (float*)d_out);
}

// Round 4
// 86.711 us; speedup vs baseline: 3.3615x; 3.3615x over previous
//
#include <hip/hip_runtime.h>
#include <cstdint>
#include <cstddef>

#define NTOT   22743     // 1083 + 4332 + 17328
#define N1     1083
#define N12    5415
#define BATCH  64
#define KCAND  512
#define NSEG   16        // segments per image
#define SEGLEN 1422      // ceil(NTOT/NSEG)
#define CAPS   384       // per-(b,c,seg) capacity (expected ~114, 3.4x headroom)
#define CAP    4096      // per-(b,c) total candidate capacity in nms LDS
#define MAXPC  100
#define MAXTOT 100

__device__ __forceinline__ float sigmoidf(float x) { return 1.0f / (1.0f + expf(-x)); }

// ---------------------------------------------------------------- kernel 1
// filter: block = (image b, segment s). Scores computed in-block, candidates
// appended to LDS lists (wave-aggregated LDS atomics), then written to a
// PRIVATE global slot with plain stores. No global atomics anywhere.
__global__ __launch_bounds__(256) void score_filter_kernel(
    const float* __restrict__ p1, const float* __restrict__ p2,
    const float* __restrict__ p3, uint2* __restrict__ cand,
    uint32_t* __restrict__ counts)
{
  const int blk  = blockIdx.x;
  const int b    = blk >> 4;            // image
  const int s    = blk & 15;            // segment
  const int tid  = threadIdx.x;
  const int lane = tid & 63;

  __shared__ uint2    lst[2][CAPS];
  __shared__ uint32_t lcnt[2];

  if (tid < 2) lcnt[tid] = 0u;
  __syncthreads();

  const int beg = s * SEGLEN;
  int end = beg + SEGLEN; if (end > NTOT) end = NTOT;

  for (int i0 = beg + tid; i0 < beg + SEGLEN; i0 += 256) {
    float s0 = 0.f, s1 = 0.f;
    const bool act = (i0 < end);
    if (act) {
      const float* p; int local, per;
      if (i0 < N1)       { p = p1; local = i0;        per = 1083; }
      else if (i0 < N12) { p = p2; local = i0 - N1;   per = 4332; }
      else               { p = p3; local = i0 - N12;  per = 17328; }
      const float* q = p + ((size_t)b * per + local) * 7;
      float q4 = q[4];
      if (q4 > 0.f) {                 // sig(q4)<=0.5 -> product < 0.5 strictly
        float obj = sigmoidf(q4);
        s0 = obj * sigmoidf(q[5]);
        s1 = obj * sigmoidf(q[6]);
      }
    }
    #pragma unroll
    for (int c = 0; c < 2; c++) {
      float sc = (c == 0) ? s0 : s1;
      bool pred = sc > 0.5f;
      unsigned long long m = __ballot(pred ? 1 : 0);
      if (m != 0ull) {
        int leader = (int)__ffsll(m) - 1;
        uint32_t base = 0u;
        if (lane == leader) base = atomicAdd(&lcnt[c], (uint32_t)__popcll(m));
        base = (uint32_t)__shfl((int)base, leader);
        if (pred) {
          uint32_t off = base + (uint32_t)__popcll(m & ((1ull << lane) - 1ull));
          if (off < CAPS) lst[c][off] = make_uint2(__float_as_uint(sc), (uint32_t)i0);
        }
      }
    }
  }
  __syncthreads();

  #pragma unroll
  for (int c = 0; c < 2; c++) {
    uint32_t cnt = lcnt[c]; if (cnt > CAPS) cnt = CAPS;
    uint2* dst = cand + ((size_t)((b * 2 + c) * NSEG + s)) * CAPS;
    for (uint32_t i = tid; i < cnt; i += 256) dst[i] = lst[c][i];
    if (tid == 0) counts[(b * 2 + c) * NSEG + s] = cnt;
  }
}

// box decode for global candidate index i of image b
__device__ void decode_box(const float* __restrict__ p1, const float* __restrict__ p2,
                           const float* __restrict__ p3, const float* __restrict__ anch,
                           int b, int i, float bb[4])
{
  const float* p; int local, g, abase, per;
  if (i < N1)       { p = p1; local = i;       g = 19; abase = 6; per = 1083; }
  else if (i < N12) { p = p2; local = i - N1;  g = 38; abase = 3; per = 4332; }
  else              { p = p3; local = i - N12; g = 76; abase = 0; per = 17328; }
  const float* q = p + ((size_t)b * per + local) * 7;
  int a    = local % 3;
  int cell = local / 3;
  int col  = cell % g;
  int row  = cell / g;
  float aw = anch[(abase + a) * 2 + 0];
  float ah = anch[(abase + a) * 2 + 1];
  float x = (sigmoidf(q[0]) + (float)col) / (float)g;
  float y = (sigmoidf(q[1]) + (float)row) / (float)g;
  float w = expf(q[2]) * aw;
  float h = expf(q[3]) * ah;
  float x1 = x - w * 0.5f;
  float y1 = y - h * 0.5f;
  bb[0] = x1; bb[1] = y1; bb[2] = x1 + w; bb[3] = y1 + h;
}

// ---------------------------------------------------------------- kernel 2
// one block (512 thr) per (image, class): concat segment lists, radix-select
// 512th key, collect >= K, rank-by-count sort (1 barrier), decode boxes,
// register-kept-list NMS on wave 0, ballot compaction.
__global__ __launch_bounds__(512) void nms_kernel(
    const uint2* __restrict__ cand, const uint32_t* __restrict__ counts,
    const float* __restrict__ p1, const float* __restrict__ p2,
    const float* __restrict__ p3, const float* __restrict__ anch,
    float* __restrict__ selScore, float* __restrict__ selBox,
    int* __restrict__ selRank, int* __restrict__ selCount)
{
  const int bc   = blockIdx.x;   // b*2 + c
  const int b    = bc >> 1;
  const int tid  = threadIdx.x;
  const int lane = tid & 63;

  __shared__ uint2    kv[CAP];          // 32 KB concatenated candidate list
  __shared__ uint2    ukv[1024];        //  8 KB collected (unsorted)
  __shared__ uint32_t skey[512];
  __shared__ uint32_t sidx[512];
  __shared__ float    bxs[512][4];
  __shared__ float    sarea[512];
  __shared__ uint32_t pos[512];
  __shared__ uint32_t hist[256];
  __shared__ uint32_t svar[8];

  // ---- concat the 16 private segment lists
  int off = 0;
  for (int s = 0; s < NSEG; s++) {
    int cs = (int)counts[bc * NSEG + s]; if (cs > CAPS) cs = CAPS;
    const uint2* src = cand + ((size_t)(bc * NSEG + s)) * CAPS;
    for (int i = tid; i < cs; i += 512) {
      int d = off + i;
      if (d < CAP) kv[d] = src[i];
    }
    off += cs;
  }
  int n = (off < CAP) ? off : CAP;

  if (tid == 0) { svar[0] = 0x3F000000u; svar[2] = KCAND; svar[4] = 0u; }
  if (tid < 512) { skey[tid] = 0u; sidx[tid] = 0xFFFFFFFFu; }
  __syncthreads();

  // ---- radix select (LDS): exact key of the 512th largest.
  // keys in (0x3F000000, 0x3F800000) -> top byte fixed 0x3F, scan bytes 2,1,0
  uint32_t K = 0u;
  if (n > KCAND) {
    #pragma unroll
    for (int p = 0; p < 3; p++) {
      const int shift = 16 - 8 * p;
      const uint32_t maskB = (p == 0) ? 0xFF000000u : (p == 1) ? 0xFFFF0000u : 0xFFFFFF00u;
      if (tid < 256) hist[tid] = 0u;
      __syncthreads();
      const uint32_t prefix = svar[0];
      for (int i = tid; i < n; i += 512) {
        uint32_t k = kv[i].x;
        if ((k & maskB) == prefix) atomicAdd(&hist[(k >> shift) & 255u], 1u);
      }
      __syncthreads();
      if (tid < 64) {                       // wave-parallel suffix-scan select
        uint32_t h0 = hist[lane * 4 + 0], h1 = hist[lane * 4 + 1];
        uint32_t h2 = hist[lane * 4 + 2], h3 = hist[lane * 4 + 3];
        uint32_t s3 = h3, s2 = h2 + s3, s1 = h1 + s2, s0 = h0 + s1;
        uint32_t acc = s0;
        #pragma unroll
        for (int o = 1; o < 64; o <<= 1) {
          uint32_t v = __shfl_down(acc, (unsigned)o);
          acc += (lane + o < 64) ? v : 0u;
        }
        uint32_t above = acc - s0;          // sum over bins >= (lane+1)*4
        uint32_t S0 = above + s0, S1 = above + s1, S2 = above + s2, S3 = above + s3, S4 = above;
        uint32_t nd = svar[2];
        if (S0 >= nd && S1 < nd) { svar[0] = prefix | ((uint32_t)(lane * 4 + 0) << shift); svar[2] = nd - S1; }
        if (S1 >= nd && S2 < nd) { svar[0] = prefix | ((uint32_t)(lane * 4 + 1) << shift); svar[2] = nd - S2; }
        if (S2 >= nd && S3 < nd) { svar[0] = prefix | ((uint32_t)(lane * 4 + 2) << shift); svar[2] = nd - S3; }
        if (S3 >= nd && S4 < nd) { svar[0] = prefix | ((uint32_t)(lane * 4 + 3) << shift); svar[2] = nd - S4; }
      }
      __syncthreads();
    }
    K = svar[0];
  }

  // ---- collect keys >= K (ballot-aggregated appends; ~513 entries)
  const int nr = (n + 511) & ~511;
  for (int i = tid; i < nr; i += 512) {
    bool pred = (i < n) && (kv[i].x >= K);
    unsigned long long m = __ballot(pred ? 1 : 0);
    if (m != 0ull) {
      int leader = (int)__ffsll(m) - 1;
      uint32_t base = 0u;
      if (lane == leader) base = atomicAdd(&svar[4], (uint32_t)__popcll(m));
      base = (uint32_t)__shfl((int)base, leader);
      if (pred) {
        uint32_t q = base + (uint32_t)__popcll(m & ((1ull << lane) - 1ull));
        if (q < 1024u) ukv[q] = kv[i];
      }
    }
  }
  __syncthreads();
  int mcnt = (int)svar[4]; if (mcnt > 1024) mcnt = 1024;

  // ---- rank-by-count sort: desc by key, ties asc by index (1 barrier)
  for (int t = tid; t < mcnt; t += 512) {
    uint2 e = ukv[t];
    int rank = 0;
    #pragma unroll 4
    for (int j = 0; j < mcnt; j++) {
      uint2 f = ukv[j];
      rank += (int)((f.x > e.x) || (f.x == e.x && f.y < e.y));
    }
    if (rank < 512) { skey[rank] = e.x; sidx[rank] = e.y; }
  }
  __syncthreads();

  const int limit = (n < KCAND) ? n : KCAND;   // all entries < limit have score > 0.5

  // ---- decode boxes for ranks [0, 512)
  if (tid < 512) {
    float bb[4] = {0.f, 0.f, 0.f, 0.f};
    if (tid < limit) decode_box(p1, p2, p3, anch, b, (int)sidx[tid], bb);
    bxs[tid][0] = bb[0]; bxs[tid][1] = bb[1]; bxs[tid][2] = bb[2]; bxs[tid][3] = bb[3];
    sarea[tid] = fmaxf(bb[2] - bb[0], 0.f) * fmaxf(bb[3] - bb[1], 0.f);
  }
  __syncthreads();

  // ---- greedy NMS on wave 0; kept list lives in registers (2 slots/lane)
  if (tid < 64) {
    float k0x1 = 0.f, k0y1 = 0.f, k0x2 = 0.f, k0y2 = 0.f, k0a = 0.f;
    float k1x1 = 0.f, k1y1 = 0.f, k1x2 = 0.f, k1y2 = 0.f, k1a = 0.f;
    int kept = 0;
    uint32_t keepbits = 0u;
    float c0 = 0.f, c1 = 0.f, c2 = 0.f, c3 = 0.f, ca = 0.f;
    if (limit > 0) {
      float4 cb = *(const float4*)bxs[0];
      c0 = cb.x; c1 = cb.y; c2 = cb.z; c3 = cb.w; ca = sarea[0];
    }
    for (int i = 0; i < limit; i++) {
      int ip = (i + 1 < limit) ? (i + 1) : i;
      float4 nb = *(const float4*)bxs[ip];       // prefetch next (broadcast read)
      float na = sarea[ip];
      bool ov;
      {
        float iw = fmaxf(fminf(c2, k0x2) - fmaxf(c0, k0x1), 0.f);
        float ih = fmaxf(fminf(c3, k0y2) - fmaxf(c1, k0y1), 0.f);
        float inter = iw * ih;
        float uni = fmaxf(ca + k0a - inter, 1e-9f);
        ov = (lane < kept) && (inter / uni > 0.5f);
      }
      {
        float iw = fmaxf(fminf(c2, k1x2) - fmaxf(c0, k1x1), 0.f);
        float ih = fmaxf(fminf(c3, k1y2) - fmaxf(c1, k1y1), 0.f);
        float inter = iw * ih;
        float uni = fmaxf(ca + k1a - inter, 1e-9f);
        ov |= (64 + lane < kept) && (inter / uni > 0.5f);
      }
      if (!__any(ov)) {
        if (lane == (kept & 63)) {
          if (kept < 64) { k0x1 = c0; k0y1 = c1; k0x2 = c2; k0y2 = c3; k0a = ca; }
          else           { k1x1 = c0; k1y1 = c1; k1x2 = c2; k1y2 = c3; k1a = ca; }
        }
        if (lane == (i & 63)) keepbits |= (1u << (i >> 6));
        kept++;
        if (kept >= MAXPC) break;    // cumsum(keep) <= 100 drops anything later
      }
      c0 = nb.x; c1 = nb.y; c2 = nb.z; c3 = nb.w; ca = na;
    }
    // ---- ballot-based compaction positions
    uint32_t total = 0u;
    #pragma unroll
    for (int t = 0; t < 8; t++) {
      unsigned long long m = __ballot((int)((keepbits >> t) & 1u));
      uint32_t pre = total + (uint32_t)__popcll(m & ((1ull << lane) - 1ull));
      pos[t * 64 + lane] = ((keepbits >> t) & 1u) ? pre : 0xFFFFFFFFu;
      total += (uint32_t)__popcll(m);
    }
    if (lane == 0) selCount[bc] = (int)total;   // <= 100 by construction
  }
  __syncthreads();

  // ---- write kept entries (order preserved)
  if (tid < 512) {
    uint32_t p = pos[tid];
    if (p < MAXPC) {
      selScore[bc * MAXPC + p] = __uint_as_float(skey[tid]);
      selRank[bc * MAXPC + p]  = tid;
      float* o = &selBox[(size_t)(bc * MAXPC + p) * 4];
      o[0] = bxs[tid][0]; o[1] = bxs[tid][1]; o[2] = bxs[tid][2]; o[3] = bxs[tid][3];
    }
  }
}

// ---------------------------------------------------------------- kernel 3
// per image: merge the two class lists (<=200), exact top-100 by
// (score desc, flat index asc) via rank-by-count, write outputs.
__global__ __launch_bounds__(256) void merge_kernel(
    const float* __restrict__ selScore, const float* __restrict__ selBox,
    const int* __restrict__ selRank, const int* __restrict__ selCount,
    float* __restrict__ out)
{
  const int b   = blockIdx.x;
  const int tid = threadIdx.x;
  __shared__ float    es[200];
  __shared__ uint32_t ek[200];
  __shared__ float    eb[200][4];
  const int c0  = selCount[b * 2 + 0];
  const int c1  = selCount[b * 2 + 1];
  const int tot = c0 + c1;                      // <= 200

  if (tid < tot) {
    int cls  = (tid < c0) ? 0 : 1;
    int slot = (cls == 0) ? tid : (tid - c0);
    int src  = (b * 2 + cls) * MAXPC + slot;
    es[tid] = selScore[src];
    ek[tid] = (uint32_t)(cls * KCAND + selRank[src]);   // flat index in (2,512)
    eb[tid][0] = selBox[(size_t)src * 4 + 0];
    eb[tid][1] = selBox[(size_t)src * 4 + 1];
    eb[tid][2] = selBox[(size_t)src * 4 + 2];
    eb[tid][3] = selBox[(size_t)src * 4 + 3];
  }
  __syncthreads();

  float* outBoxes  = out;
  float* outScores = out + (size_t)BATCH * MAXTOT * 4;
  float* outCls    = outScores + (size_t)BATCH * MAXTOT;
  float* outCnt    = outCls + (size_t)BATCH * MAXTOT;
  const int filled = (tot < MAXTOT) ? tot : MAXTOT;

  if (tid < tot) {
    float    s  = es[tid];
    uint32_t fk = ek[tid];
    int rank = 0;
    for (int j = 0; j < tot; j++)
      rank += (int)((es[j] > s) || (es[j] == s && ek[j] < fk));
    if (rank < MAXTOT) {                       // kept: s > 0.5 > 0 always
      outScores[b * MAXTOT + rank] = s;
      outCls[b * MAXTOT + rank]    = (float)(fk >> 9);
      float* ob = &outBoxes[(size_t)(b * MAXTOT + rank) * 4];
      ob[0] = fminf(fmaxf(eb[tid][0], 0.f), 1.f);
      ob[1] = fminf(fmaxf(eb[tid][1], 0.f), 1.f);
      ob[2] = fminf(fmaxf(eb[tid][2], 0.f), 1.f);
      ob[3] = fminf(fmaxf(eb[tid][3], 0.f), 1.f);
    }
  }
  if (tid >= filled && tid < MAXTOT) {         // zero-fill unused slots
    outScores[b * MAXTOT + tid] = 0.f;
    outCls[b * MAXTOT + tid]    = 0.f;
    float* ob = &outBoxes[(size_t)(b * MAXTOT + tid) * 4];
    ob[0] = 0.f; ob[1] = 0.f; ob[2] = 0.f; ob[3] = 0.f;
  }
  if (tid == 0) outCnt[b] = (float)filled;
}

// ---------------------------------------------------------------- launch
extern "C" void kernel_launch(void* const* d_in, const int* in_sizes, int n_in,
                              void* d_out, int out_size, void* d_ws, size_t ws_size,
                              hipStream_t stream)
{
  const float* p1   = (const float*)d_in[0];
  const float* p2   = (const float*)d_in[1];
  const float* p3   = (const float*)d_in[2];
  const float* anch = (const float*)d_in[3];

  uint8_t* ws = (uint8_t*)d_ws;
  uint32_t* counts  = (uint32_t*)ws;                                // 128*16 u32
  uint2*    cand    = (uint2*)(ws + 16384);                         // 128*16*384 uint2 = 6 MB
  float*    selScore= (float*)(ws + 16384 + (size_t)128 * NSEG * CAPS * 8);
  float*    selBox  = selScore + BATCH * 2 * MAXPC;                 // 128*100*4 f32
  int*      selRank = (int*)(selBox + (size_t)BATCH * 2 * MAXPC * 4);
  int*      selCount= selRank + BATCH * 2 * MAXPC;                  // 128 int

  score_filter_kernel<<<BATCH * NSEG, 256, 0, stream>>>(p1, p2, p3, cand, counts);
  nms_kernel<<<BATCH * 2, 512, 0, stream>>>(cand, counts, p1, p2, p3, anch,
                                            selScore, selBox, selRank, selCount);
  merge_kernel<<<BATCH, 256, 0, stream>>>(selScore, selBox, selRank, selCount,
                                          (float*)d_out);
}